// Round 12
// baseline (565.889 us; speedup 1.0000x reference)
//
#include <hip/hip_runtime.h>

#define CMID 32
#define CIN 128
#define HNB 32
#define KP 15
#define NEG 0.1f
#define EPS 1e-5f
#define GRID 512          // 2 blocks/CU x 256 CU; occupancy capacity is 3/CU
                          // (launch_bounds 256,3 + 40KB LDS) -> all resident
#define GQ (GRID / 4)     // 128 row-block strides for the col-split phases

// ---------------------------------------------------------------------------
// Manual persistent-kernel grid barrier (graph-capture-safe, no cooperative
// launch). Monotonic counter in workspace, re-zeroed by the captured memset.
// Release/acquire at agent scope emits the L2 writeback/invalidate needed for
// cross-XCD visibility of plain stores (y1, x2) on gfx950.
// ---------------------------------------------------------------------------
__device__ __forceinline__ void grid_barrier(unsigned int* bar, unsigned int target, int t)
{
    __threadfence();      // flush this thread's stores toward coherent point
    __syncthreads();      // all block stores issued before arrival
    if (t == 0) {
        __hip_atomic_fetch_add(bar, 1u, __ATOMIC_RELEASE, __HIP_MEMORY_SCOPE_AGENT);
        while (__hip_atomic_load(bar, __ATOMIC_ACQUIRE, __HIP_MEMORY_SCOPE_AGENT) < target)
            __builtin_amdgcn_s_sleep(8);
    }
    __syncthreads();      // block proceeds only after t0 saw the full count
}

// ---------------------------------------------------------------------------
// Shared-memory union across phases. sizeof(SB) = 39968 B is the max.
// ---------------------------------------------------------------------------
struct SA {                      // phase 1 (gemm1): 33.8 KB
    float AsT[32 * 128];
    float Bs[128 * 32];
    float red[256];
};
struct SB {                      // phase 2 (kpinv): 39.97 KB
    float a1s[32], b1s[32];
    float wg1[32 * 8];
    float bg1[8];
    float wg2[8 * 30];
    float bg2[32];
    float kps[48];
    float vbuf[4][2][1024];      // [wave][p][c*32 + swz(h)]
    float aux[4][2][144];        // center[0:32) h1[32:40) w[40:72) s[72:136)
};
struct SD {                      // phases 3/4 (zstats/final): 22.0 KB
    float ST[32 * 128];
    float Ws[32 * 32];
    float acs[32], bcs[32];
    float a2s[32], b2s[32];
    float red[256];
};
union SU { SA a; SB b; SD d; };

// ---------------------------------------------------------------------------
// Fused: P1 gemm1+stats | bar | P2 kpinv+x2stats | bar | P3 zstats | bar |
//        P4 final. Phase bodies are the round-6-verified kernels.
// ---------------------------------------------------------------------------
__global__ __launch_bounds__(256, 3) void fused(
    const float* __restrict__ q_pts, const float* __restrict__ s_pts,
    const float* __restrict__ s_feats, const int* __restrict__ idx,
    const float* __restrict__ kp,
    const float* __restrict__ w_u1, const float* __restrict__ g_u1,
    const float* __restrict__ b_u1,
    const float* __restrict__ w_g1, const float* __restrict__ b_g1,
    const float* __restrict__ w_g2, const float* __restrict__ b_g2,
    const float* __restrict__ g_c, const float* __restrict__ b_c,
    const float* __restrict__ w_u2, const float* __restrict__ g_u2,
    const float* __restrict__ b_u2,
    float* __restrict__ y1, float* __restrict__ x2, float* __restrict__ st,
    unsigned int* __restrict__ bar,
    float* __restrict__ out, int M)
{
    __shared__ __align__(16) SU sm;
    int t = threadIdx.x;
    int nb1 = (M + 127) / 128;

    // ================= Phase 1: y1 = s_feats @ w_u1 + stats =================
    {
        for (int i = t; i < 128 * 32; i += 256) sm.a.Bs[i] = w_u1[i];
        int tx = t & 7, ty = t >> 3;
        int srow = t & 127, shh = t >> 7;
        for (int bb = blockIdx.x; bb < nb1; bb += GRID) {
            int m0 = bb * 128;
            float acc[4][4] = {{0.f}};
            for (int ch = 0; ch < 4; ++ch) {
                __syncthreads();
                int gr = m0 + srow;
                const float4* ap = (const float4*)(s_feats + (size_t)gr * CIN + ch * 32 + shh * 16);
                float4 f0, f1, f2, f3;
                if (gr < M) { f0 = ap[0]; f1 = ap[1]; f2 = ap[2]; f3 = ap[3]; }
                else { f0 = f1 = f2 = f3 = make_float4(0.f, 0.f, 0.f, 0.f); }
                int cb = shh * 16;
                sm.a.AsT[(cb + 0) * 128 + srow] = f0.x;  sm.a.AsT[(cb + 1) * 128 + srow] = f0.y;
                sm.a.AsT[(cb + 2) * 128 + srow] = f0.z;  sm.a.AsT[(cb + 3) * 128 + srow] = f0.w;
                sm.a.AsT[(cb + 4) * 128 + srow] = f1.x;  sm.a.AsT[(cb + 5) * 128 + srow] = f1.y;
                sm.a.AsT[(cb + 6) * 128 + srow] = f1.z;  sm.a.AsT[(cb + 7) * 128 + srow] = f1.w;
                sm.a.AsT[(cb + 8) * 128 + srow] = f2.x;  sm.a.AsT[(cb + 9) * 128 + srow] = f2.y;
                sm.a.AsT[(cb + 10) * 128 + srow] = f2.z; sm.a.AsT[(cb + 11) * 128 + srow] = f2.w;
                sm.a.AsT[(cb + 12) * 128 + srow] = f3.x; sm.a.AsT[(cb + 13) * 128 + srow] = f3.y;
                sm.a.AsT[(cb + 14) * 128 + srow] = f3.z; sm.a.AsT[(cb + 15) * 128 + srow] = f3.w;
                __syncthreads();
                const float* bsp = sm.a.Bs + (ch * 32) * 32 + tx * 4;
#pragma unroll
                for (int jl = 0; jl < 32; ++jl) {
                    float4 av = *(const float4*)(sm.a.AsT + jl * 128 + ty * 4);
                    float4 bv = *(const float4*)(bsp + jl * 32);
                    acc[0][0] += av.x * bv.x; acc[0][1] += av.x * bv.y; acc[0][2] += av.x * bv.z; acc[0][3] += av.x * bv.w;
                    acc[1][0] += av.y * bv.x; acc[1][1] += av.y * bv.y; acc[1][2] += av.y * bv.z; acc[1][3] += av.y * bv.w;
                    acc[2][0] += av.z * bv.x; acc[2][1] += av.z * bv.y; acc[2][2] += av.z * bv.z; acc[2][3] += av.z * bv.w;
                    acc[3][0] += av.w * bv.x; acc[3][1] += av.w * bv.y; acc[3][2] += av.w * bv.z; acc[3][3] += av.w * bv.w;
                }
            }
#pragma unroll
            for (int i = 0; i < 4; ++i) {
                int r = m0 + ty * 4 + i;
                if (r < M)
                    *(float4*)(y1 + (size_t)r * CMID + tx * 4) =
                        make_float4(acc[i][0], acc[i][1], acc[i][2], acc[i][3]);
            }
            float s4[4], q4[4];
#pragma unroll
            for (int e = 0; e < 4; ++e) {
                s4[e] = acc[0][e] + acc[1][e] + acc[2][e] + acc[3][e];
                q4[e] = acc[0][e] * acc[0][e] + acc[1][e] * acc[1][e]
                      + acc[2][e] * acc[2][e] + acc[3][e] * acc[3][e];
            }
#pragma unroll
            for (int off = 8; off <= 32; off <<= 1) {
#pragma unroll
                for (int e = 0; e < 4; ++e) {
                    s4[e] += __shfl_xor(s4[e], off);
                    q4[e] += __shfl_xor(q4[e], off);
                }
            }
            int lw = t >> 6, ll = t & 63;
            if (ll < 8) {
#pragma unroll
                for (int e = 0; e < 4; ++e) {
                    sm.a.red[(lw * 8 + ll) * 8 + e] = s4[e];
                    sm.a.red[(lw * 8 + ll) * 8 + 4 + e] = q4[e];
                }
            }
            __syncthreads();
            if (t < 64) {
                int tx2 = t >> 3, k = t & 7;
                float v = sm.a.red[(0 * 8 + tx2) * 8 + k] + sm.a.red[(1 * 8 + tx2) * 8 + k]
                        + sm.a.red[(2 * 8 + tx2) * 8 + k] + sm.a.red[(3 * 8 + tx2) * 8 + k];
                int col = tx2 * 4 + (k & 3);
                atomicAdd(&st[(k < 4 ? 0 : 32) + col], v);
            }
        }
    }
    grid_barrier(bar, GRID, t);

    // ================= Phase 2: KPInv conv + x2 stats =================
    {
        if (t < 32) {
            float mean = st[t] * (1.0f / M);
            float var  = st[32 + t] * (1.0f / M) - mean * mean;
            float inv  = rsqrtf(var + EPS);
            float a = g_u1[t] * inv;
            sm.b.a1s[t] = a;
            sm.b.b1s[t] = b_u1[t] - mean * a;
        }
        sm.b.wg1[t] = w_g1[t];
        if (t < 8)   sm.b.bg1[t] = b_g1[t];
        if (t < 240) sm.b.wg2[t] = w_g2[t];
        if (t < 30)  sm.b.bg2[t] = b_g2[t];
        else if (t < 32) sm.b.bg2[t] = 0.f;
        if (t < KP * 3) sm.b.kps[t] = kp[t];
        __syncthreads();

        int wave = t >> 6, lane = t & 63;
        int p = lane >> 5;
        int q = lane & 31;
        float* vb = &sm.b.vbuf[wave][p][0];
        float* ax = &sm.b.aux[wave][p][0];
        float ssum = 0.f, ssq = 0.f;
        int ng = (M + 7) / 8;

        for (int g = blockIdx.x; g < ng; g += GRID) {
            int m = g * 8 + wave * 2 + p;
            bool valid = (m < M);
            int mm = valid ? m : 0;

            // -------- P2.1 (q = h): gather + BN + lrelu, infl --------
            int h = q;
            int n = idx[(size_t)mm * HNB + h];
            float qx = q_pts[mm * 3 + 0], qy = q_pts[mm * 3 + 1], qz = q_pts[mm * 3 + 2];
            float dx = s_pts[n * 3 + 0] - qx;
            float dy = s_pts[n * 3 + 1] - qy;
            float dz = s_pts[n * 3 + 2] - qz;
            float infl[KP];
#pragma unroll
            for (int k = 0; k < KP; ++k) {
                float ex = dx - sm.b.kps[k * 3 + 0];
                float ey = dy - sm.b.kps[k * 3 + 1];
                float ez = dz - sm.b.kps[k * 3 + 2];
                float d = sqrtf(ex * ex + ey * ey + ez * ez);
                infl[k] = fmaxf(1.0f - d, 0.f);
            }
            {
                const float4* row = (const float4*)(y1 + (size_t)n * CMID);
                int hq4 = h >> 2, h3 = h & 3;
#pragma unroll
                for (int jj = 0; jj < 8; ++jj) {
                    float4 f = row[jj];
                    float vv[4] = {f.x, f.y, f.z, f.w};
#pragma unroll
                    for (int e = 0; e < 4; ++e) {
                        int c = jj * 4 + e;
                        float x = vv[e] * sm.b.a1s[c] + sm.b.b1s[c];
                        x = fmaxf(x, NEG * x);
                        vb[(c << 5) + ((hq4 ^ (c & 7)) << 2) + h3] = x;
                    }
                }
            }
            __builtin_amdgcn_wave_barrier();

            // -------- P2.2 (q = c): center max, MLP1, MLP2 --------
            {
                int c = q;
                int c7 = c & 7;
                const float* vrow = vb + (c << 5);
                float cm = -1e30f;
#pragma unroll
                for (int j = 0; j < 8; ++j) {
                    const float4 f = *(const float4*)(vrow + ((j ^ c7) << 2));
                    cm = fmaxf(fmaxf(fmaxf(cm, f.x), fmaxf(f.y, f.z)), f.w);
                }
                ax[c] = cm;
                __builtin_amdgcn_wave_barrier();

                int jm = c & 7;
                float acc = sm.b.bg1[jm];
#pragma unroll
                for (int cc = 0; cc < 8; ++cc) {
                    const float4 ce = *(const float4*)(ax + (cc << 2));
                    acc += ce.x * sm.b.wg1[(cc * 4 + 0) * 8 + jm];
                    acc += ce.y * sm.b.wg1[(cc * 4 + 1) * 8 + jm];
                    acc += ce.z * sm.b.wg1[(cc * 4 + 2) * 8 + jm];
                    acc += ce.w * sm.b.wg1[(cc * 4 + 3) * 8 + jm];
                }
                float h1v = fmaxf(acc, NEG * acc);
                if (c < 8) ax[32 + c] = h1v;
                __builtin_amdgcn_wave_barrier();

                float wv = 0.f;
                if (c < 30) {
                    const float4 ha = *(const float4*)(ax + 32);
                    const float4 hb = *(const float4*)(ax + 36);
                    wv = sm.b.bg2[c]
                       + ha.x * sm.b.wg2[0 * 30 + c] + ha.y * sm.b.wg2[1 * 30 + c]
                       + ha.z * sm.b.wg2[2 * 30 + c] + ha.w * sm.b.wg2[3 * 30 + c]
                       + hb.x * sm.b.wg2[4 * 30 + c] + hb.y * sm.b.wg2[5 * 30 + c]
                       + hb.z * sm.b.wg2[6 * 30 + c] + hb.w * sm.b.wg2[7 * 30 + c];
                }
                ax[40 + c] = wv;
            }
            __builtin_amdgcn_wave_barrier();

            // -------- P2.3 (q = h): s_g[h] --------
            {
                float wf[32];
#pragma unroll
                for (int j = 0; j < 8; ++j) {
                    const float4 wc = *(const float4*)(ax + 40 + (j << 2));
                    wf[j * 4 + 0] = wc.x; wf[j * 4 + 1] = wc.y;
                    wf[j * 4 + 2] = wc.z; wf[j * 4 + 3] = wc.w;
                }
                float s0 = 0.f, s1 = 0.f;
#pragma unroll
                for (int k = 0; k < KP; ++k) {
                    s0 += infl[k] * wf[2 * k + 0];
                    s1 += infl[k] * wf[2 * k + 1];
                }
                ax[72 + q]  = s0;
                ax[104 + q] = s1;
            }
            __builtin_amdgcn_wave_barrier();

            // -------- P2.4 (q = c): out + stats accumulate --------
            {
                int c = q;
                int c7 = c & 7;
                const float* sbuf = ax + 72 + ((c >> 4) << 5);
                const float* vrow = vb + (c << 5);
                float o = 0.f;
#pragma unroll
                for (int j = 0; j < 8; ++j) {
                    const float4 vv = *(const float4*)(vrow + ((j ^ c7) << 2));
                    const float4 ss = *(const float4*)(sbuf + (j << 2));
                    o += vv.x * ss.x + vv.y * ss.y + vv.z * ss.z + vv.w * ss.w;
                }
                if (valid) {
                    x2[(size_t)m * CMID + c] = o;
                    ssum += o; ssq += o * o;
                }
            }
            __builtin_amdgcn_wave_barrier();   // protect vb reuse next iteration
        }
        // block reduction of x2 stats (fuses old k4)
        __syncthreads();
        float* red2 = (float*)&sm;
        red2[t] = ssum; __syncthreads();
        if (t < 32) { float s = 0.f; for (int i = 0; i < 8; ++i) s += red2[t + 32 * i]; atomicAdd(&st[64 + t], s); }
        __syncthreads();
        red2[t] = ssq; __syncthreads();
        if (t < 32) { float s = 0.f; for (int i = 0; i < 8; ++i) s += red2[t + 32 * i]; atomicAdd(&st[96 + t], s); }
    }
    grid_barrier(bar, 2 * GRID, t);

    // ================= Phase 3: z-stats (k6) =================
    int cb3 = blockIdx.x & 3;
    {
        if (t < 32) {
            float mean = st[64 + t] * (1.0f / M);
            float var  = st[96 + t] * (1.0f / M) - mean * mean;
            float inv  = rsqrtf(var + EPS);
            float a = g_c[t] * inv;
            sm.d.acs[t] = a; sm.d.bcs[t] = b_c[t] - mean * a;
        }
        for (int i = t; i < 32 * 32; i += 256)
            sm.d.Ws[i] = w_u2[(i >> 5) * CIN + cb3 * 32 + (i & 31)];

        int srow = t & 127, shh = t >> 7;
        int tx = t & 7, ty = t >> 3;
        for (int bbr = blockIdx.x >> 2; bbr < nb1; bbr += GQ) {
            int m0 = bbr * 128;
            __syncthreads();
            int gr = m0 + srow;
            const float4* xp = (const float4*)(x2 + (size_t)gr * CMID + shh * 16);
            float4 f0, f1, f2, f3;
            if (gr < M) { f0 = xp[0]; f1 = xp[1]; f2 = xp[2]; f3 = xp[3]; }
            else { f0 = f1 = f2 = f3 = make_float4(0.f, 0.f, 0.f, 0.f); }
            {
                float vv[16] = {f0.x, f0.y, f0.z, f0.w, f1.x, f1.y, f1.z, f1.w,
                                f2.x, f2.y, f2.z, f2.w, f3.x, f3.y, f3.z, f3.w};
                int cbse = shh * 16;
#pragma unroll
                for (int e = 0; e < 16; ++e) {
                    int c = cbse + e;
                    float x = vv[e] * sm.d.acs[c] + sm.d.bcs[c];
                    x = fmaxf(x, NEG * x);
                    sm.d.ST[c * 128 + srow] = (gr < M) ? x : 0.f;
                }
            }
            __syncthreads();
            float acc[4][4] = {{0.f}};
#pragma unroll
            for (int j = 0; j < 32; ++j) {
                float4 av = *(const float4*)(sm.d.ST + j * 128 + ty * 4);
                float4 bv = *(const float4*)(sm.d.Ws + j * 32 + tx * 4);
                acc[0][0] += av.x * bv.x; acc[0][1] += av.x * bv.y; acc[0][2] += av.x * bv.z; acc[0][3] += av.x * bv.w;
                acc[1][0] += av.y * bv.x; acc[1][1] += av.y * bv.y; acc[1][2] += av.y * bv.z; acc[1][3] += av.y * bv.w;
                acc[2][0] += av.z * bv.x; acc[2][1] += av.z * bv.y; acc[2][2] += av.z * bv.z; acc[2][3] += av.z * bv.w;
                acc[3][0] += av.w * bv.x; acc[3][1] += av.w * bv.y; acc[3][2] += av.w * bv.z; acc[3][3] += av.w * bv.w;
            }
            float s4[4], q4[4];
#pragma unroll
            for (int e = 0; e < 4; ++e) {
                s4[e] = acc[0][e] + acc[1][e] + acc[2][e] + acc[3][e];
                q4[e] = acc[0][e] * acc[0][e] + acc[1][e] * acc[1][e]
                      + acc[2][e] * acc[2][e] + acc[3][e] * acc[3][e];
            }
#pragma unroll
            for (int off = 8; off <= 32; off <<= 1) {
#pragma unroll
                for (int e = 0; e < 4; ++e) {
                    s4[e] += __shfl_xor(s4[e], off);
                    q4[e] += __shfl_xor(q4[e], off);
                }
            }
            int lw = t >> 6, ll = t & 63;
            if (ll < 8) {
#pragma unroll
                for (int e = 0; e < 4; ++e) {
                    sm.d.red[(lw * 8 + ll) * 8 + e] = s4[e];
                    sm.d.red[(lw * 8 + ll) * 8 + 4 + e] = q4[e];
                }
            }
            __syncthreads();
            if (t < 64) {
                int tx2 = t >> 3, k = t & 7;
                float v = sm.d.red[(0 * 8 + tx2) * 8 + k] + sm.d.red[(1 * 8 + tx2) * 8 + k]
                        + sm.d.red[(2 * 8 + tx2) * 8 + k] + sm.d.red[(3 * 8 + tx2) * 8 + k];
                int col = cb3 * 32 + tx2 * 4 + (k & 3);
                atomicAdd(&st[(k < 4 ? 128 : 256) + col], v);
            }
        }
    }
    grid_barrier(bar, 3 * GRID, t);

    // ================= Phase 4: final (k8) =================
    {
        if (t < 32) {
            float mean = st[64 + t] * (1.0f / M);
            float var  = st[96 + t] * (1.0f / M) - mean * mean;
            float inv  = rsqrtf(var + EPS);
            float a = g_c[t] * inv;
            sm.d.acs[t] = a; sm.d.bcs[t] = b_c[t] - mean * a;
            int c = cb3 * 32 + t;
            float mean2 = st[128 + c] * (1.0f / M);
            float var2  = st[256 + c] * (1.0f / M) - mean2 * mean2;
            float inv2  = rsqrtf(var2 + EPS);
            float a2 = g_u2[c] * inv2;
            sm.d.a2s[t] = a2; sm.d.b2s[t] = b_u2[c] - mean2 * a2;
        }
        for (int i = t; i < 32 * 32; i += 256)
            sm.d.Ws[i] = w_u2[(i >> 5) * CIN + cb3 * 32 + (i & 31)];

        int srow = t & 127, shh = t >> 7;
        int tx = t & 7, ty = t >> 3;
        for (int bbr = blockIdx.x >> 2; bbr < nb1; bbr += GQ) {
            int m0 = bbr * 128;
            __syncthreads();
            int gr = m0 + srow;
            const float4* xp = (const float4*)(x2 + (size_t)gr * CMID + shh * 16);
            float4 f0, f1, f2, f3;
            if (gr < M) { f0 = xp[0]; f1 = xp[1]; f2 = xp[2]; f3 = xp[3]; }
            else { f0 = f1 = f2 = f3 = make_float4(0.f, 0.f, 0.f, 0.f); }
            {
                float vv[16] = {f0.x, f0.y, f0.z, f0.w, f1.x, f1.y, f1.z, f1.w,
                                f2.x, f2.y, f2.z, f2.w, f3.x, f3.y, f3.z, f3.w};
                int cbse = shh * 16;
#pragma unroll
                for (int e = 0; e < 16; ++e) {
                    int c = cbse + e;
                    float x = vv[e] * sm.d.acs[c] + sm.d.bcs[c];
                    x = fmaxf(x, NEG * x);
                    sm.d.ST[c * 128 + srow] = (gr < M) ? x : 0.f;
                }
            }
            __syncthreads();
            float acc[4][4] = {{0.f}};
#pragma unroll
            for (int j = 0; j < 32; ++j) {
                float4 av = *(const float4*)(sm.d.ST + j * 128 + ty * 4);
                float4 bv = *(const float4*)(sm.d.Ws + j * 32 + tx * 4);
                acc[0][0] += av.x * bv.x; acc[0][1] += av.x * bv.y; acc[0][2] += av.x * bv.z; acc[0][3] += av.x * bv.w;
                acc[1][0] += av.y * bv.x; acc[1][1] += av.y * bv.y; acc[1][2] += av.y * bv.z; acc[1][3] += av.y * bv.w;
                acc[2][0] += av.z * bv.x; acc[2][1] += av.z * bv.y; acc[2][2] += av.z * bv.z; acc[2][3] += av.z * bv.w;
                acc[3][0] += av.w * bv.x; acc[3][1] += av.w * bv.y; acc[3][2] += av.w * bv.z; acc[3][3] += av.w * bv.w;
            }
            int lc = tx * 4;
            float a0 = sm.d.a2s[lc + 0], a1 = sm.d.a2s[lc + 1], a2v = sm.d.a2s[lc + 2], a3 = sm.d.a2s[lc + 3];
            float bb0 = sm.d.b2s[lc + 0], bb1 = sm.d.b2s[lc + 1], bb2 = sm.d.b2s[lc + 2], bb3 = sm.d.b2s[lc + 3];
#pragma unroll
            for (int i = 0; i < 4; ++i) {
                int r = m0 + ty * 4 + i;
                if (r < M) {
                    size_t gi = (size_t)r * CIN + cb3 * 32 + lc;
                    float4 sf = *(const float4*)(s_feats + gi);
                    float v0 = acc[i][0] * a0 + bb0 + sf.x;
                    float v1 = acc[i][1] * a1 + bb1 + sf.y;
                    float v2 = acc[i][2] * a2v + bb2 + sf.z;
                    float v3 = acc[i][3] * a3 + bb3 + sf.w;
                    v0 = fmaxf(v0, NEG * v0); v1 = fmaxf(v1, NEG * v1);
                    v2 = fmaxf(v2, NEG * v2); v3 = fmaxf(v3, NEG * v3);
                    *(float4*)(out + gi) = make_float4(v0, v1, v2, v3);
                }
            }
        }
    }
}

extern "C" void kernel_launch(void* const* d_in, const int* in_sizes, int n_in,
                              void* d_out, int out_size, void* d_ws, size_t ws_size,
                              hipStream_t stream) {
    const float* q_pts   = (const float*)d_in[0];
    const float* s_pts   = (const float*)d_in[1];
    const float* s_feats = (const float*)d_in[2];
    const int*   idx     = (const int*)d_in[3];
    const float* kp      = (const float*)d_in[4];
    const float* w_u1    = (const float*)d_in[5];
    const float* g_u1    = (const float*)d_in[6];
    const float* b_u1    = (const float*)d_in[7];
    const float* w_g1    = (const float*)d_in[8];
    const float* b_g1    = (const float*)d_in[9];
    const float* w_g2    = (const float*)d_in[10];
    const float* b_g2    = (const float*)d_in[11];
    const float* g_c     = (const float*)d_in[12];
    const float* b_c     = (const float*)d_in[13];
    const float* w_u2    = (const float*)d_in[14];
    const float* g_u2    = (const float*)d_in[15];
    const float* b_u2    = (const float*)d_in[16];

    int M = in_sizes[3] / HNB;   // 50000

    float* ws = (float*)d_ws;
    float* y1 = ws;                        // M*32
    float* x2 = ws + (size_t)M * CMID;     // M*32
    float* st = ws + (size_t)M * 2 * CMID; // 384 floats stats + barrier counter
    unsigned int* bar = (unsigned int*)(st + 384);

    // zero stats + barrier counter (captured into the graph -> re-zeroed
    // on every replay)
    hipMemsetAsync(st, 0, 512 * sizeof(float), stream);

    fused<<<GRID, 256, 0, stream>>>(
        q_pts, s_pts, s_feats, idx, kp,
        w_u1, g_u1, b_u1, w_g1, b_g1, w_g2, b_g2,
        g_c, b_c, w_u2, g_u2, b_u2,
        y1, x2, st, bar, (float*)d_out, M);
}

// Round 13
// 333.035 us; speedup vs baseline: 1.6992x; 1.6992x over previous
//
#include <hip/hip_runtime.h>

#define CMID 32
#define CIN 128
#define HNB 32
#define KP 15
#define NEG 0.1f
#define EPS 1e-5f

// ---------------------------------------------------------------------------
// K1: y1 = s_feats @ w_u1  (M x 128 @ 128 x 32) + per-channel sum/sumsq stats.
// Register-tiled (round-6 verified).
// ---------------------------------------------------------------------------
__global__ __launch_bounds__(256) void k1_gemm1(
    const float* __restrict__ A, const float* __restrict__ B,
    float* __restrict__ y1, float* __restrict__ st, int M)
{
    __shared__ __align__(16) float AsT[32 * 128];
    __shared__ __align__(16) float Bs[128 * 32];
    __shared__ __align__(16) float red[256];
    int t = threadIdx.x;
    for (int i = t; i < 128 * 32; i += 256) Bs[i] = B[i];

    int m0 = blockIdx.x * 128;
    int tx = t & 7, ty = t >> 3;
    int srow = t & 127, shh = t >> 7;
    float acc[4][4] = {{0.f}};

    for (int ch = 0; ch < 4; ++ch) {
        __syncthreads();
        int gr = m0 + srow;
        const float4* ap = (const float4*)(A + (size_t)gr * CIN + ch * 32 + shh * 16);
        float4 f0, f1, f2, f3;
        if (gr < M) { f0 = ap[0]; f1 = ap[1]; f2 = ap[2]; f3 = ap[3]; }
        else { f0 = f1 = f2 = f3 = make_float4(0.f, 0.f, 0.f, 0.f); }
        {
            int cb = shh * 16;
            AsT[(cb + 0) * 128 + srow] = f0.x;  AsT[(cb + 1) * 128 + srow] = f0.y;
            AsT[(cb + 2) * 128 + srow] = f0.z;  AsT[(cb + 3) * 128 + srow] = f0.w;
            AsT[(cb + 4) * 128 + srow] = f1.x;  AsT[(cb + 5) * 128 + srow] = f1.y;
            AsT[(cb + 6) * 128 + srow] = f1.z;  AsT[(cb + 7) * 128 + srow] = f1.w;
            AsT[(cb + 8) * 128 + srow] = f2.x;  AsT[(cb + 9) * 128 + srow] = f2.y;
            AsT[(cb + 10) * 128 + srow] = f2.z; AsT[(cb + 11) * 128 + srow] = f2.w;
            AsT[(cb + 12) * 128 + srow] = f3.x; AsT[(cb + 13) * 128 + srow] = f3.y;
            AsT[(cb + 14) * 128 + srow] = f3.z; AsT[(cb + 15) * 128 + srow] = f3.w;
        }
        __syncthreads();
        const float* bsp = Bs + (ch * 32) * 32 + tx * 4;
#pragma unroll
        for (int jl = 0; jl < 32; ++jl) {
            float4 av = *(const float4*)(AsT + jl * 128 + ty * 4);
            float4 bv = *(const float4*)(bsp + jl * 32);
            acc[0][0] += av.x * bv.x; acc[0][1] += av.x * bv.y; acc[0][2] += av.x * bv.z; acc[0][3] += av.x * bv.w;
            acc[1][0] += av.y * bv.x; acc[1][1] += av.y * bv.y; acc[1][2] += av.y * bv.z; acc[1][3] += av.y * bv.w;
            acc[2][0] += av.z * bv.x; acc[2][1] += av.z * bv.y; acc[2][2] += av.z * bv.z; acc[2][3] += av.z * bv.w;
            acc[3][0] += av.w * bv.x; acc[3][1] += av.w * bv.y; acc[3][2] += av.w * bv.z; acc[3][3] += av.w * bv.w;
        }
    }
#pragma unroll
    for (int i = 0; i < 4; ++i) {
        int r = m0 + ty * 4 + i;
        if (r < M)
            *(float4*)(y1 + (size_t)r * CMID + tx * 4) =
                make_float4(acc[i][0], acc[i][1], acc[i][2], acc[i][3]);
    }
    float s4[4], q4[4];
#pragma unroll
    for (int e = 0; e < 4; ++e) {
        s4[e] = acc[0][e] + acc[1][e] + acc[2][e] + acc[3][e];
        q4[e] = acc[0][e] * acc[0][e] + acc[1][e] * acc[1][e]
              + acc[2][e] * acc[2][e] + acc[3][e] * acc[3][e];
    }
#pragma unroll
    for (int off = 8; off <= 32; off <<= 1) {
#pragma unroll
        for (int e = 0; e < 4; ++e) {
            s4[e] += __shfl_xor(s4[e], off);
            q4[e] += __shfl_xor(q4[e], off);
        }
    }
    int lw = t >> 6, ll = t & 63;
    if (ll < 8) {
#pragma unroll
        for (int e = 0; e < 4; ++e) {
            red[(lw * 8 + ll) * 8 + e] = s4[e];
            red[(lw * 8 + ll) * 8 + 4 + e] = q4[e];
        }
    }
    __syncthreads();
    if (t < 64) {
        int tx2 = t >> 3, k = t & 7;
        float v = red[(0 * 8 + tx2) * 8 + k] + red[(1 * 8 + tx2) * 8 + k]
                + red[(2 * 8 + tx2) * 8 + k] + red[(3 * 8 + tx2) * 8 + k];
        int col = tx2 * 4 + (k & 3);
        atomicAdd(&st[(k < 4 ? 0 : 32) + col], v);
    }
}

// ---------------------------------------------------------------------------
// K3: KPInv conv (round-6 verified) + x2-stats epilogue folded in (kills k4).
// Each thread ends phase 4 holding one o = x2[m][c]; block-reduce per channel
// (c = t&31, 8 contributors at t = c+32*i) then 32 atomics -> st[64:128).
// ---------------------------------------------------------------------------
__global__ __launch_bounds__(256, 4) void k3_kpinv(
    const float* __restrict__ y1, float* __restrict__ st,
    const float* __restrict__ q_pts, const float* __restrict__ s_pts,
    const int* __restrict__ idx, const float* __restrict__ kp,
    const float* __restrict__ g_u1, const float* __restrict__ b_u1,
    const float* __restrict__ w_g1, const float* __restrict__ b_g1,
    const float* __restrict__ w_g2, const float* __restrict__ b_g2,
    float* __restrict__ x2, int M)
{
    __shared__ __align__(16) float a1s[32], b1s[32];
    __shared__ __align__(16) float wg1[32 * 8];
    __shared__ __align__(16) float bg1[8];
    __shared__ __align__(16) float wg2[8 * 30];
    __shared__ __align__(16) float bg2[32];
    __shared__ __align__(16) float kps[KP * 3 + 1];
    __shared__ __align__(16) float vbuf[4][2][1024];
    __shared__ __align__(16) float aux[4][2][144];

    int t = threadIdx.x;
    if (t < 32) {
        float mean = st[t] * (1.0f / M);
        float var  = st[32 + t] * (1.0f / M) - mean * mean;
        float inv  = rsqrtf(var + EPS);
        float a = g_u1[t] * inv;
        a1s[t] = a;
        b1s[t] = b_u1[t] - mean * a;
    }
    wg1[t & 255] = w_g1[t & 255];
    if (t < 8)   bg1[t] = b_g1[t];
    if (t < 240) wg2[t] = w_g2[t];
    if (t < 30)  bg2[t] = b_g2[t];
    else if (t < 32) bg2[t] = 0.f;
    if (t < KP * 3) kps[t] = kp[t];
    __syncthreads();

    int wave = t >> 6, lane = t & 63;
    int p = lane >> 5;
    int q = lane & 31;
    int m = blockIdx.x * 8 + wave * 2 + p;
    bool valid = (m < M);
    int mm = valid ? m : 0;
    float* vb = &vbuf[wave][p][0];
    float* ax = &aux[wave][p][0];
    float osum = 0.f;

    // ---------------- Phase 1: q = h ----------------
    int h = q;
    int n = idx[(size_t)mm * HNB + h];
    float qx = q_pts[mm * 3 + 0], qy = q_pts[mm * 3 + 1], qz = q_pts[mm * 3 + 2];
    float dx = s_pts[n * 3 + 0] - qx;
    float dy = s_pts[n * 3 + 1] - qy;
    float dz = s_pts[n * 3 + 2] - qz;

    float infl[KP];
#pragma unroll
    for (int k = 0; k < KP; ++k) {
        float ex = dx - kps[k * 3 + 0];
        float ey = dy - kps[k * 3 + 1];
        float ez = dz - kps[k * 3 + 2];
        float d = sqrtf(ex * ex + ey * ey + ez * ez);
        infl[k] = fmaxf(1.0f - d, 0.f);
    }

    {
        const float4* row = (const float4*)(y1 + (size_t)n * CMID);
        int hq4 = h >> 2, h3 = h & 3;
#pragma unroll
        for (int jj = 0; jj < 8; ++jj) {
            float4 f = row[jj];
            float vv[4] = {f.x, f.y, f.z, f.w};
#pragma unroll
            for (int e = 0; e < 4; ++e) {
                int c = jj * 4 + e;
                float x = vv[e] * a1s[c] + b1s[c];
                x = fmaxf(x, NEG * x);
                vb[(c << 5) + ((hq4 ^ (c & 7)) << 2) + h3] = x;
            }
        }
    }
    __builtin_amdgcn_wave_barrier();

    // ---------------- Phase 2: q = c ----------------
    {
        int c = q;
        int c7 = c & 7;
        const float* vrow = vb + (c << 5);
        float cm = -1e30f;
#pragma unroll
        for (int j = 0; j < 8; ++j) {
            const float4 f = *(const float4*)(vrow + ((j ^ c7) << 2));
            cm = fmaxf(fmaxf(fmaxf(cm, f.x), fmaxf(f.y, f.z)), f.w);
        }
        ax[c] = cm;
        __builtin_amdgcn_wave_barrier();

        int jm = c & 7;
        float acc = bg1[jm];
#pragma unroll
        for (int cc = 0; cc < 8; ++cc) {
            const float4 ce = *(const float4*)(ax + (cc << 2));
            acc += ce.x * wg1[(cc * 4 + 0) * 8 + jm];
            acc += ce.y * wg1[(cc * 4 + 1) * 8 + jm];
            acc += ce.z * wg1[(cc * 4 + 2) * 8 + jm];
            acc += ce.w * wg1[(cc * 4 + 3) * 8 + jm];
        }
        float h1v = fmaxf(acc, NEG * acc);
        if (c < 8) ax[32 + c] = h1v;
        __builtin_amdgcn_wave_barrier();

        float wv = 0.f;
        if (c < 30) {
            const float4 ha = *(const float4*)(ax + 32);
            const float4 hb = *(const float4*)(ax + 36);
            wv = bg2[c]
               + ha.x * wg2[0 * 30 + c] + ha.y * wg2[1 * 30 + c]
               + ha.z * wg2[2 * 30 + c] + ha.w * wg2[3 * 30 + c]
               + hb.x * wg2[4 * 30 + c] + hb.y * wg2[5 * 30 + c]
               + hb.z * wg2[6 * 30 + c] + hb.w * wg2[7 * 30 + c];
        }
        ax[40 + c] = wv;
    }
    __builtin_amdgcn_wave_barrier();

    // ---------------- Phase 3: q = h ----------------
    {
        float wf[32];
#pragma unroll
        for (int j = 0; j < 8; ++j) {
            const float4 wc = *(const float4*)(ax + 40 + (j << 2));
            wf[j * 4 + 0] = wc.x; wf[j * 4 + 1] = wc.y;
            wf[j * 4 + 2] = wc.z; wf[j * 4 + 3] = wc.w;
        }
        float s0 = 0.f, s1 = 0.f;
#pragma unroll
        for (int k = 0; k < KP; ++k) {
            s0 += infl[k] * wf[2 * k + 0];
            s1 += infl[k] * wf[2 * k + 1];
        }
        ax[72 + q]  = s0;
        ax[104 + q] = s1;
    }
    __builtin_amdgcn_wave_barrier();

    // ---------------- Phase 4: q = c ----------------
    {
        int c = q;
        int c7 = c & 7;
        const float* sbuf = ax + 72 + ((c >> 4) << 5);
        const float* vrow = vb + (c << 5);
        float o = 0.f;
#pragma unroll
        for (int j = 0; j < 8; ++j) {
            const float4 vv = *(const float4*)(vrow + ((j ^ c7) << 2));
            const float4 ss = *(const float4*)(sbuf + (j << 2));
            o += vv.x * ss.x + vv.y * ss.y + vv.z * ss.z + vv.w * ss.w;
        }
        if (valid) {
            x2[(size_t)m * CMID + c] = o;
            osum = o;
        }
    }

    // ---------------- Epilogue: x2 stats (old k4) ----------------
    __syncthreads();                       // all waves done with vbuf
    float* red = &vbuf[0][0][0];           // reuse as 256-float scratch
    red[t] = osum;
    __syncthreads();
    if (t < 32) {
        float s = 0.f;
#pragma unroll
        for (int i = 0; i < 8; ++i) s += red[t + 32 * i];
        atomicAdd(&st[64 + t], s);
    }
    __syncthreads();
    red[t] = osum * osum;
    __syncthreads();
    if (t < 32) {
        float s = 0.f;
#pragma unroll
        for (int i = 0; i < 8; ++i) s += red[t + 32 * i];
        atomicAdd(&st[96 + t], s);
    }
}

// ---------------------------------------------------------------------------
// K6: z = lrelu(bn_c(x2)) @ w_u2; stats -> st[128:384) AND store z into
// out (used as scratch) so k8 never recomputes the GEMM.
// ---------------------------------------------------------------------------
__global__ __launch_bounds__(256) void k6_zstats(
    const float* __restrict__ x2, const float* __restrict__ w_u2,
    const float* __restrict__ g_c, const float* __restrict__ b_c,
    float* __restrict__ st, float* __restrict__ zout, int M)
{
    __shared__ __align__(16) float ST[32 * 128];
    __shared__ __align__(16) float Ws[32 * 32];
    __shared__ __align__(16) float acs[32], bcs[32];
    __shared__ __align__(16) float red[256];
    int t = threadIdx.x;
    int cb = blockIdx.y;
    int m0 = blockIdx.x * 128;
    if (t < 32) {
        float mean = st[64 + t] * (1.0f / M);
        float var  = st[96 + t] * (1.0f / M) - mean * mean;
        float inv  = rsqrtf(var + EPS);
        float a = g_c[t] * inv;
        acs[t] = a; bcs[t] = b_c[t] - mean * a;
    }
    for (int i = t; i < 32 * 32; i += 256)
        Ws[i] = w_u2[(i >> 5) * CIN + cb * 32 + (i & 31)];
    __syncthreads();

    int srow = t & 127, shh = t >> 7;
    int gr = m0 + srow;
    const float4* xp = (const float4*)(x2 + (size_t)gr * CMID + shh * 16);
    float4 f0, f1, f2, f3;
    if (gr < M) { f0 = xp[0]; f1 = xp[1]; f2 = xp[2]; f3 = xp[3]; }
    else { f0 = f1 = f2 = f3 = make_float4(0.f, 0.f, 0.f, 0.f); }
    {
        float vv[16] = {f0.x, f0.y, f0.z, f0.w, f1.x, f1.y, f1.z, f1.w,
                        f2.x, f2.y, f2.z, f2.w, f3.x, f3.y, f3.z, f3.w};
        int cbse = shh * 16;
#pragma unroll
        for (int e = 0; e < 16; ++e) {
            int c = cbse + e;
            float x = vv[e] * acs[c] + bcs[c];
            x = fmaxf(x, NEG * x);
            ST[c * 128 + srow] = (gr < M) ? x : 0.f;
        }
    }
    __syncthreads();

    int tx = t & 7, ty = t >> 3;
    float acc[4][4] = {{0.f}};
#pragma unroll
    for (int j = 0; j < 32; ++j) {
        float4 av = *(const float4*)(ST + j * 128 + ty * 4);
        float4 bv = *(const float4*)(Ws + j * 32 + tx * 4);
        acc[0][0] += av.x * bv.x; acc[0][1] += av.x * bv.y; acc[0][2] += av.x * bv.z; acc[0][3] += av.x * bv.w;
        acc[1][0] += av.y * bv.x; acc[1][1] += av.y * bv.y; acc[1][2] += av.y * bv.z; acc[1][3] += av.y * bv.w;
        acc[2][0] += av.z * bv.x; acc[2][1] += av.z * bv.y; acc[2][2] += av.z * bv.z; acc[2][3] += av.z * bv.w;
        acc[3][0] += av.w * bv.x; acc[3][1] += av.w * bv.y; acc[3][2] += av.w * bv.z; acc[3][3] += av.w * bv.w;
    }
    // store z (scratch in out buffer)
#pragma unroll
    for (int i = 0; i < 4; ++i) {
        int r = m0 + ty * 4 + i;
        if (r < M)
            *(float4*)(zout + (size_t)r * CIN + cb * 32 + tx * 4) =
                make_float4(acc[i][0], acc[i][1], acc[i][2], acc[i][3]);
    }
    // stats of z (pad rows contribute 0)
    float s4[4], q4[4];
#pragma unroll
    for (int e = 0; e < 4; ++e) {
        s4[e] = acc[0][e] + acc[1][e] + acc[2][e] + acc[3][e];
        q4[e] = acc[0][e] * acc[0][e] + acc[1][e] * acc[1][e]
              + acc[2][e] * acc[2][e] + acc[3][e] * acc[3][e];
    }
#pragma unroll
    for (int off = 8; off <= 32; off <<= 1) {
#pragma unroll
        for (int e = 0; e < 4; ++e) {
            s4[e] += __shfl_xor(s4[e], off);
            q4[e] += __shfl_xor(q4[e], off);
        }
    }
    int lw = t >> 6, ll = t & 63;
    if (ll < 8) {
#pragma unroll
        for (int e = 0; e < 4; ++e) {
            red[(lw * 8 + ll) * 8 + e] = s4[e];
            red[(lw * 8 + ll) * 8 + 4 + e] = q4[e];
        }
    }
    __syncthreads();
    if (t < 64) {
        int tx2 = t >> 3, k = t & 7;
        float v = red[(0 * 8 + tx2) * 8 + k] + red[(1 * 8 + tx2) * 8 + k]
                + red[(2 * 8 + tx2) * 8 + k] + red[(3 * 8 + tx2) * 8 + k];
        int col = cb * 32 + tx2 * 4 + (k & 3);
        atomicAdd(&st[(k < 4 ? 128 : 256) + col], v);
    }
}

// ---------------------------------------------------------------------------
// K8: elementwise final. z already in out (scratch): out = lrelu(z*a2+b2 +
// s_feats), in place. Pure memory-bound (~77 MB traffic).
// ---------------------------------------------------------------------------
__global__ __launch_bounds__(256) void k8_elem(
    const float* __restrict__ s_feats,
    const float* __restrict__ g_u2, const float* __restrict__ b_u2,
    const float* __restrict__ st, float* __restrict__ out, int M)
{
    __shared__ float a2s[128], b2s[128];
    int t = threadIdx.x;
    if (t < 128) {
        float mean = st[128 + t] * (1.0f / M);
        float var  = st[256 + t] * (1.0f / M) - mean * mean;
        float inv  = rsqrtf(var + EPS);
        float a = g_u2[t] * inv;
        a2s[t] = a; b2s[t] = b_u2[t] - mean * a;
    }
    __syncthreads();
    size_t total = (size_t)M * 32;   // float4 count
    float4* o4 = (float4*)out;
    const float4* s4 = (const float4*)s_feats;
    for (size_t i = (size_t)blockIdx.x * 256 + t; i < total;
         i += (size_t)gridDim.x * 256) {
        float4 z = o4[i];
        float4 sf = s4[i];
        int c = ((int)(i & 31)) * 4;
        float v0 = z.x * a2s[c + 0] + b2s[c + 0] + sf.x;
        float v1 = z.y * a2s[c + 1] + b2s[c + 1] + sf.y;
        float v2 = z.z * a2s[c + 2] + b2s[c + 2] + sf.z;
        float v3 = z.w * a2s[c + 3] + b2s[c + 3] + sf.w;
        v0 = fmaxf(v0, NEG * v0); v1 = fmaxf(v1, NEG * v1);
        v2 = fmaxf(v2, NEG * v2); v3 = fmaxf(v3, NEG * v3);
        o4[i] = make_float4(v0, v1, v2, v3);
    }
}

extern "C" void kernel_launch(void* const* d_in, const int* in_sizes, int n_in,
                              void* d_out, int out_size, void* d_ws, size_t ws_size,
                              hipStream_t stream) {
    const float* q_pts   = (const float*)d_in[0];
    const float* s_pts   = (const float*)d_in[1];
    const float* s_feats = (const float*)d_in[2];
    const int*   idx     = (const int*)d_in[3];
    const float* kp      = (const float*)d_in[4];
    const float* w_u1    = (const float*)d_in[5];
    const float* g_u1    = (const float*)d_in[6];
    const float* b_u1    = (const float*)d_in[7];
    const float* w_g1    = (const float*)d_in[8];
    const float* b_g1    = (const float*)d_in[9];
    const float* w_g2    = (const float*)d_in[10];
    const float* b_g2    = (const float*)d_in[11];
    const float* g_c     = (const float*)d_in[12];
    const float* b_c     = (const float*)d_in[13];
    const float* w_u2    = (const float*)d_in[14];
    const float* g_u2    = (const float*)d_in[15];
    const float* b_u2    = (const float*)d_in[16];

    int M = in_sizes[3] / HNB;   // 50000

    float* ws = (float*)d_ws;
    float* y1 = ws;                        // M*32
    float* x2 = ws + (size_t)M * CMID;     // M*32
    float* st = ws + (size_t)M * 2 * CMID; // 384 floats of stats
    float* out = (float*)d_out;

    hipMemsetAsync(st, 0, 384 * sizeof(float), stream);

    int nbr = (M + 127) / 128;   // 391
    k1_gemm1<<<nbr, 256, 0, stream>>>(s_feats, w_u1, y1, st, M);
    k3_kpinv<<<(M + 7) / 8, 256, 0, stream>>>(y1, st, q_pts, s_pts, idx, kp,
                                              g_u1, b_u1, w_g1, b_g1, w_g2, b_g2,
                                              x2, M);
    k6_zstats<<<dim3(nbr, 4), 256, 0, stream>>>(x2, w_u2, g_c, b_c, st, out, M);
    k8_elem<<<2048, 256, 0, stream>>>(s_feats, g_u2, b_u2, st, out, M);
}

// Round 14
// 242.417 us; speedup vs baseline: 2.3344x; 1.3738x over previous
//
#include <hip/hip_runtime.h>

#define CMID 32
#define CIN 128
#define HNB 32
#define KP 15
#define NEG 0.1f
#define EPS 1e-5f

// ---------------------------------------------------------------------------
// K1: y1 = s_feats @ w_u1  (M x 128 @ 128 x 32) + per-channel sum/sumsq stats.
// Register-tiled (round-6 verified).
// ---------------------------------------------------------------------------
__global__ __launch_bounds__(256) void k1_gemm1(
    const float* __restrict__ A, const float* __restrict__ B,
    float* __restrict__ y1, float* __restrict__ st, int M)
{
    __shared__ __align__(16) float AsT[32 * 128];
    __shared__ __align__(16) float Bs[128 * 32];
    __shared__ __align__(16) float red[256];
    int t = threadIdx.x;
    for (int i = t; i < 128 * 32; i += 256) Bs[i] = B[i];

    int m0 = blockIdx.x * 128;
    int tx = t & 7, ty = t >> 3;
    int srow = t & 127, shh = t >> 7;
    float acc[4][4] = {{0.f}};

    for (int ch = 0; ch < 4; ++ch) {
        __syncthreads();
        int gr = m0 + srow;
        const float4* ap = (const float4*)(A + (size_t)gr * CIN + ch * 32 + shh * 16);
        float4 f0, f1, f2, f3;
        if (gr < M) { f0 = ap[0]; f1 = ap[1]; f2 = ap[2]; f3 = ap[3]; }
        else { f0 = f1 = f2 = f3 = make_float4(0.f, 0.f, 0.f, 0.f); }
        {
            int cb = shh * 16;
            AsT[(cb + 0) * 128 + srow] = f0.x;  AsT[(cb + 1) * 128 + srow] = f0.y;
            AsT[(cb + 2) * 128 + srow] = f0.z;  AsT[(cb + 3) * 128 + srow] = f0.w;
            AsT[(cb + 4) * 128 + srow] = f1.x;  AsT[(cb + 5) * 128 + srow] = f1.y;
            AsT[(cb + 6) * 128 + srow] = f1.z;  AsT[(cb + 7) * 128 + srow] = f1.w;
            AsT[(cb + 8) * 128 + srow] = f2.x;  AsT[(cb + 9) * 128 + srow] = f2.y;
            AsT[(cb + 10) * 128 + srow] = f2.z; AsT[(cb + 11) * 128 + srow] = f2.w;
            AsT[(cb + 12) * 128 + srow] = f3.x; AsT[(cb + 13) * 128 + srow] = f3.y;
            AsT[(cb + 14) * 128 + srow] = f3.z; AsT[(cb + 15) * 128 + srow] = f3.w;
        }
        __syncthreads();
        const float* bsp = Bs + (ch * 32) * 32 + tx * 4;
#pragma unroll
        for (int jl = 0; jl < 32; ++jl) {
            float4 av = *(const float4*)(AsT + jl * 128 + ty * 4);
            float4 bv = *(const float4*)(bsp + jl * 32);
            acc[0][0] += av.x * bv.x; acc[0][1] += av.x * bv.y; acc[0][2] += av.x * bv.z; acc[0][3] += av.x * bv.w;
            acc[1][0] += av.y * bv.x; acc[1][1] += av.y * bv.y; acc[1][2] += av.y * bv.z; acc[1][3] += av.y * bv.w;
            acc[2][0] += av.z * bv.x; acc[2][1] += av.z * bv.y; acc[2][2] += av.z * bv.z; acc[2][3] += av.z * bv.w;
            acc[3][0] += av.w * bv.x; acc[3][1] += av.w * bv.y; acc[3][2] += av.w * bv.z; acc[3][3] += av.w * bv.w;
        }
    }
#pragma unroll
    for (int i = 0; i < 4; ++i) {
        int r = m0 + ty * 4 + i;
        if (r < M)
            *(float4*)(y1 + (size_t)r * CMID + tx * 4) =
                make_float4(acc[i][0], acc[i][1], acc[i][2], acc[i][3]);
    }
    float s4[4], q4[4];
#pragma unroll
    for (int e = 0; e < 4; ++e) {
        s4[e] = acc[0][e] + acc[1][e] + acc[2][e] + acc[3][e];
        q4[e] = acc[0][e] * acc[0][e] + acc[1][e] * acc[1][e]
              + acc[2][e] * acc[2][e] + acc[3][e] * acc[3][e];
    }
#pragma unroll
    for (int off = 8; off <= 32; off <<= 1) {
#pragma unroll
        for (int e = 0; e < 4; ++e) {
            s4[e] += __shfl_xor(s4[e], off);
            q4[e] += __shfl_xor(q4[e], off);
        }
    }
    int lw = t >> 6, ll = t & 63;
    if (ll < 8) {
#pragma unroll
        for (int e = 0; e < 4; ++e) {
            red[(lw * 8 + ll) * 8 + e] = s4[e];
            red[(lw * 8 + ll) * 8 + 4 + e] = q4[e];
        }
    }
    __syncthreads();
    if (t < 64) {
        int tx2 = t >> 3, k = t & 7;
        float v = red[(0 * 8 + tx2) * 8 + k] + red[(1 * 8 + tx2) * 8 + k]
                + red[(2 * 8 + tx2) * 8 + k] + red[(3 * 8 + tx2) * 8 + k];
        int col = tx2 * 4 + (k & 3);
        atomicAdd(&st[(k < 4 ? 0 : 32) + col], v);
    }
}

// ---------------------------------------------------------------------------
// K3: KPInv conv, role-switching layout (round-6 verified, 65.5 us).
// NO stats epilogue: 6250 blocks x 64 atomics onto 64 addresses serialized
// L2 RMWs and cost +100 us (round-13 lesson). k4 does stats with 128 blocks.
// ---------------------------------------------------------------------------
__global__ __launch_bounds__(256, 4) void k3_kpinv(
    const float* __restrict__ y1, const float* __restrict__ st,
    const float* __restrict__ q_pts, const float* __restrict__ s_pts,
    const int* __restrict__ idx, const float* __restrict__ kp,
    const float* __restrict__ g_u1, const float* __restrict__ b_u1,
    const float* __restrict__ w_g1, const float* __restrict__ b_g1,
    const float* __restrict__ w_g2, const float* __restrict__ b_g2,
    float* __restrict__ x2, int M)
{
    __shared__ __align__(16) float a1s[32], b1s[32];
    __shared__ __align__(16) float wg1[32 * 8];
    __shared__ __align__(16) float bg1[8];
    __shared__ __align__(16) float wg2[8 * 30];
    __shared__ __align__(16) float bg2[32];
    __shared__ __align__(16) float kps[KP * 3 + 1];
    __shared__ __align__(16) float vbuf[4][2][1024];
    __shared__ __align__(16) float aux[4][2][144];

    int t = threadIdx.x;
    if (t < 32) {
        float mean = st[t] * (1.0f / M);
        float var  = st[32 + t] * (1.0f / M) - mean * mean;
        float inv  = rsqrtf(var + EPS);
        float a = g_u1[t] * inv;
        a1s[t] = a;
        b1s[t] = b_u1[t] - mean * a;
    }
    wg1[t & 255] = w_g1[t & 255];
    if (t < 8)   bg1[t] = b_g1[t];
    if (t < 240) wg2[t] = w_g2[t];
    if (t < 30)  bg2[t] = b_g2[t];
    else if (t < 32) bg2[t] = 0.f;
    if (t < KP * 3) kps[t] = kp[t];
    __syncthreads();

    int wave = t >> 6, lane = t & 63;
    int p = lane >> 5;
    int q = lane & 31;
    int m = blockIdx.x * 8 + wave * 2 + p;
    bool valid = (m < M);
    int mm = valid ? m : 0;
    float* vb = &vbuf[wave][p][0];
    float* ax = &aux[wave][p][0];

    // ---------------- Phase 1: q = h ----------------
    int h = q;
    int n = idx[(size_t)mm * HNB + h];
    float qx = q_pts[mm * 3 + 0], qy = q_pts[mm * 3 + 1], qz = q_pts[mm * 3 + 2];
    float dx = s_pts[n * 3 + 0] - qx;
    float dy = s_pts[n * 3 + 1] - qy;
    float dz = s_pts[n * 3 + 2] - qz;

    float infl[KP];
#pragma unroll
    for (int k = 0; k < KP; ++k) {
        float ex = dx - kps[k * 3 + 0];
        float ey = dy - kps[k * 3 + 1];
        float ez = dz - kps[k * 3 + 2];
        float d = sqrtf(ex * ex + ey * ey + ez * ez);
        infl[k] = fmaxf(1.0f - d, 0.f);
    }

    {
        const float4* row = (const float4*)(y1 + (size_t)n * CMID);
        int hq4 = h >> 2, h3 = h & 3;
#pragma unroll
        for (int jj = 0; jj < 8; ++jj) {
            float4 f = row[jj];
            float vv[4] = {f.x, f.y, f.z, f.w};
#pragma unroll
            for (int e = 0; e < 4; ++e) {
                int c = jj * 4 + e;
                float x = vv[e] * a1s[c] + b1s[c];
                x = fmaxf(x, NEG * x);
                vb[(c << 5) + ((hq4 ^ (c & 7)) << 2) + h3] = x;
            }
        }
    }
    __builtin_amdgcn_wave_barrier();

    // ---------------- Phase 2: q = c ----------------
    {
        int c = q;
        int c7 = c & 7;
        const float* vrow = vb + (c << 5);
        float cm = -1e30f;
#pragma unroll
        for (int j = 0; j < 8; ++j) {
            const float4 f = *(const float4*)(vrow + ((j ^ c7) << 2));
            cm = fmaxf(fmaxf(fmaxf(cm, f.x), fmaxf(f.y, f.z)), f.w);
        }
        ax[c] = cm;
        __builtin_amdgcn_wave_barrier();

        int jm = c & 7;
        float acc = bg1[jm];
#pragma unroll
        for (int cc = 0; cc < 8; ++cc) {
            const float4 ce = *(const float4*)(ax + (cc << 2));
            acc += ce.x * wg1[(cc * 4 + 0) * 8 + jm];
            acc += ce.y * wg1[(cc * 4 + 1) * 8 + jm];
            acc += ce.z * wg1[(cc * 4 + 2) * 8 + jm];
            acc += ce.w * wg1[(cc * 4 + 3) * 8 + jm];
        }
        float h1v = fmaxf(acc, NEG * acc);
        if (c < 8) ax[32 + c] = h1v;
        __builtin_amdgcn_wave_barrier();

        float wv = 0.f;
        if (c < 30) {
            const float4 ha = *(const float4*)(ax + 32);
            const float4 hb = *(const float4*)(ax + 36);
            wv = bg2[c]
               + ha.x * wg2[0 * 30 + c] + ha.y * wg2[1 * 30 + c]
               + ha.z * wg2[2 * 30 + c] + ha.w * wg2[3 * 30 + c]
               + hb.x * wg2[4 * 30 + c] + hb.y * wg2[5 * 30 + c]
               + hb.z * wg2[6 * 30 + c] + hb.w * wg2[7 * 30 + c];
        }
        ax[40 + c] = wv;
    }
    __builtin_amdgcn_wave_barrier();

    // ---------------- Phase 3: q = h ----------------
    {
        float wf[32];
#pragma unroll
        for (int j = 0; j < 8; ++j) {
            const float4 wc = *(const float4*)(ax + 40 + (j << 2));
            wf[j * 4 + 0] = wc.x; wf[j * 4 + 1] = wc.y;
            wf[j * 4 + 2] = wc.z; wf[j * 4 + 3] = wc.w;
        }
        float s0 = 0.f, s1 = 0.f;
#pragma unroll
        for (int k = 0; k < KP; ++k) {
            s0 += infl[k] * wf[2 * k + 0];
            s1 += infl[k] * wf[2 * k + 1];
        }
        ax[72 + q]  = s0;
        ax[104 + q] = s1;
    }
    __builtin_amdgcn_wave_barrier();

    // ---------------- Phase 4: q = c ----------------
    {
        int c = q;
        int c7 = c & 7;
        const float* sbuf = ax + 72 + ((c >> 4) << 5);
        const float* vrow = vb + (c << 5);
        float o = 0.f;
#pragma unroll
        for (int j = 0; j < 8; ++j) {
            const float4 vv = *(const float4*)(vrow + ((j ^ c7) << 2));
            const float4 ss = *(const float4*)(sbuf + (j << 2));
            o += vv.x * ss.x + vv.y * ss.y + vv.z * ss.z + vv.w * ss.w;
        }
        if (valid) x2[(size_t)m * CMID + c] = o;
    }
}

// ---------------------------------------------------------------------------
// K4: per-channel sum/sumsq over x2 (32 channels) -> st[64:96), st[96:128).
// 128 blocks -> only 8K atomics (round-6 verified, ~3 us).
// ---------------------------------------------------------------------------
__global__ __launch_bounds__(256) void k4_stats32(
    const float* __restrict__ x2, float* __restrict__ st, int M)
{
    int t = threadIdx.x;
    int c = t & 31;
    float sum = 0.f, sq = 0.f;
    for (int r = blockIdx.x * 8 + (t >> 5); r < M; r += gridDim.x * 8) {
        float v = x2[(size_t)r * CMID + c];
        sum += v; sq += v * v;
    }
    __shared__ float red[256];
    red[t] = sum; __syncthreads();
    if (t < 32) { float s = 0.f; for (int i = 0; i < 8; ++i) s += red[t + 32 * i]; atomicAdd(&st[64 + t], s); }
    __syncthreads();
    red[t] = sq; __syncthreads();
    if (t < 32) { float s = 0.f; for (int i = 0; i < 8; ++i) s += red[t + 32 * i]; atomicAdd(&st[96 + t], s); }
}

// ---------------------------------------------------------------------------
// K6: z = lrelu(bn_c(x2)) @ w_u2; stats -> st[128:384) AND store z into
// out (used as scratch) so k8 never recomputes the GEMM (round-13 verified,
// non-k3 time 187 -> 167 us).
// ---------------------------------------------------------------------------
__global__ __launch_bounds__(256) void k6_zstats(
    const float* __restrict__ x2, const float* __restrict__ w_u2,
    const float* __restrict__ g_c, const float* __restrict__ b_c,
    float* __restrict__ st, float* __restrict__ zout, int M)
{
    __shared__ __align__(16) float ST[32 * 128];
    __shared__ __align__(16) float Ws[32 * 32];
    __shared__ __align__(16) float acs[32], bcs[32];
    __shared__ __align__(16) float red[256];
    int t = threadIdx.x;
    int cb = blockIdx.y;
    int m0 = blockIdx.x * 128;
    if (t < 32) {
        float mean = st[64 + t] * (1.0f / M);
        float var  = st[96 + t] * (1.0f / M) - mean * mean;
        float inv  = rsqrtf(var + EPS);
        float a = g_c[t] * inv;
        acs[t] = a; bcs[t] = b_c[t] - mean * a;
    }
    for (int i = t; i < 32 * 32; i += 256)
        Ws[i] = w_u2[(i >> 5) * CIN + cb * 32 + (i & 31)];
    __syncthreads();

    int srow = t & 127, shh = t >> 7;
    int gr = m0 + srow;
    const float4* xp = (const float4*)(x2 + (size_t)gr * CMID + shh * 16);
    float4 f0, f1, f2, f3;
    if (gr < M) { f0 = xp[0]; f1 = xp[1]; f2 = xp[2]; f3 = xp[3]; }
    else { f0 = f1 = f2 = f3 = make_float4(0.f, 0.f, 0.f, 0.f); }
    {
        float vv[16] = {f0.x, f0.y, f0.z, f0.w, f1.x, f1.y, f1.z, f1.w,
                        f2.x, f2.y, f2.z, f2.w, f3.x, f3.y, f3.z, f3.w};
        int cbse = shh * 16;
#pragma unroll
        for (int e = 0; e < 16; ++e) {
            int c = cbse + e;
            float x = vv[e] * acs[c] + bcs[c];
            x = fmaxf(x, NEG * x);
            ST[c * 128 + srow] = (gr < M) ? x : 0.f;
        }
    }
    __syncthreads();

    int tx = t & 7, ty = t >> 3;
    float acc[4][4] = {{0.f}};
#pragma unroll
    for (int j = 0; j < 32; ++j) {
        float4 av = *(const float4*)(ST + j * 128 + ty * 4);
        float4 bv = *(const float4*)(Ws + j * 32 + tx * 4);
        acc[0][0] += av.x * bv.x; acc[0][1] += av.x * bv.y; acc[0][2] += av.x * bv.z; acc[0][3] += av.x * bv.w;
        acc[1][0] += av.y * bv.x; acc[1][1] += av.y * bv.y; acc[1][2] += av.y * bv.z; acc[1][3] += av.y * bv.w;
        acc[2][0] += av.z * bv.x; acc[2][1] += av.z * bv.y; acc[2][2] += av.z * bv.z; acc[2][3] += av.z * bv.w;
        acc[3][0] += av.w * bv.x; acc[3][1] += av.w * bv.y; acc[3][2] += av.w * bv.z; acc[3][3] += av.w * bv.w;
    }
    // store z (scratch in out buffer)
#pragma unroll
    for (int i = 0; i < 4; ++i) {
        int r = m0 + ty * 4 + i;
        if (r < M)
            *(float4*)(zout + (size_t)r * CIN + cb * 32 + tx * 4) =
                make_float4(acc[i][0], acc[i][1], acc[i][2], acc[i][3]);
    }
    // stats of z (pad rows contribute 0)
    float s4[4], q4[4];
#pragma unroll
    for (int e = 0; e < 4; ++e) {
        s4[e] = acc[0][e] + acc[1][e] + acc[2][e] + acc[3][e];
        q4[e] = acc[0][e] * acc[0][e] + acc[1][e] * acc[1][e]
              + acc[2][e] * acc[2][e] + acc[3][e] * acc[3][e];
    }
#pragma unroll
    for (int off = 8; off <= 32; off <<= 1) {
#pragma unroll
        for (int e = 0; e < 4; ++e) {
            s4[e] += __shfl_xor(s4[e], off);
            q4[e] += __shfl_xor(q4[e], off);
        }
    }
    int lw = t >> 6, ll = t & 63;
    if (ll < 8) {
#pragma unroll
        for (int e = 0; e < 4; ++e) {
            red[(lw * 8 + ll) * 8 + e] = s4[e];
            red[(lw * 8 + ll) * 8 + 4 + e] = q4[e];
        }
    }
    __syncthreads();
    if (t < 64) {
        int tx2 = t >> 3, k = t & 7;
        float v = red[(0 * 8 + tx2) * 8 + k] + red[(1 * 8 + tx2) * 8 + k]
                + red[(2 * 8 + tx2) * 8 + k] + red[(3 * 8 + tx2) * 8 + k];
        int col = cb * 32 + tx2 * 4 + (k & 3);
        atomicAdd(&st[(k < 4 ? 128 : 256) + col], v);
    }
}

// ---------------------------------------------------------------------------
// K8: elementwise final. z already in out (scratch): out = lrelu(z*a2+b2 +
// s_feats), in place. Pure memory-bound (~77 MB traffic).
// ---------------------------------------------------------------------------
__global__ __launch_bounds__(256) void k8_elem(
    const float* __restrict__ s_feats,
    const float* __restrict__ g_u2, const float* __restrict__ b_u2,
    const float* __restrict__ st, float* __restrict__ out, int M)
{
    __shared__ float a2s[128], b2s[128];
    int t = threadIdx.x;
    if (t < 128) {
        float mean = st[128 + t] * (1.0f / M);
        float var  = st[256 + t] * (1.0f / M) - mean * mean;
        float inv  = rsqrtf(var + EPS);
        float a = g_u2[t] * inv;
        a2s[t] = a; b2s[t] = b_u2[t] - mean * a;
    }
    __syncthreads();
    size_t total = (size_t)M * 32;   // float4 count
    float4* o4 = (float4*)out;
    const float4* s4 = (const float4*)s_feats;
    for (size_t i = (size_t)blockIdx.x * 256 + t; i < total;
         i += (size_t)gridDim.x * 256) {
        float4 z = o4[i];
        float4 sf = s4[i];
        int c = ((int)(i & 31)) * 4;
        float v0 = z.x * a2s[c + 0] + b2s[c + 0] + sf.x;
        float v1 = z.y * a2s[c + 1] + b2s[c + 1] + sf.y;
        float v2 = z.z * a2s[c + 2] + b2s[c + 2] + sf.z;
        float v3 = z.w * a2s[c + 3] + b2s[c + 3] + sf.w;
        v0 = fmaxf(v0, NEG * v0); v1 = fmaxf(v1, NEG * v1);
        v2 = fmaxf(v2, NEG * v2); v3 = fmaxf(v3, NEG * v3);
        o4[i] = make_float4(v0, v1, v2, v3);
    }
}

extern "C" void kernel_launch(void* const* d_in, const int* in_sizes, int n_in,
                              void* d_out, int out_size, void* d_ws, size_t ws_size,
                              hipStream_t stream) {
    const float* q_pts   = (const float*)d_in[0];
    const float* s_pts   = (const float*)d_in[1];
    const float* s_feats = (const float*)d_in[2];
    const int*   idx     = (const int*)d_in[3];
    const float* kp      = (const float*)d_in[4];
    const float* w_u1    = (const float*)d_in[5];
    const float* g_u1    = (const float*)d_in[6];
    const float* b_u1    = (const float*)d_in[7];
    const float* w_g1    = (const float*)d_in[8];
    const float* b_g1    = (const float*)d_in[9];
    const float* w_g2    = (const float*)d_in[10];
    const float* b_g2    = (const float*)d_in[11];
    const float* g_c     = (const float*)d_in[12];
    const float* b_c     = (const float*)d_in[13];
    const float* w_u2    = (const float*)d_in[14];
    const float* g_u2    = (const float*)d_in[15];
    const float* b_u2    = (const float*)d_in[16];

    int M = in_sizes[3] / HNB;   // 50000

    float* ws = (float*)d_ws;
    float* y1 = ws;                        // M*32
    float* x2 = ws + (size_t)M * CMID;     // M*32
    float* st = ws + (size_t)M * 2 * CMID; // 384 floats of stats
    float* out = (float*)d_out;

    hipMemsetAsync(st, 0, 384 * sizeof(float), stream);

    int nbr = (M + 127) / 128;   // 391
    k1_gemm1<<<nbr, 256, 0, stream>>>(s_feats, w_u1, y1, st, M);
    k3_kpinv<<<(M + 7) / 8, 256, 0, stream>>>(y1, st, q_pts, s_pts, idx, kp,
                                              g_u1, b_u1, w_g1, b_g1, w_g2, b_g2,
                                              x2, M);
    k4_stats32<<<128, 256, 0, stream>>>(x2, st, M);
    k6_zstats<<<dim3(nbr, 4), 256, 0, stream>>>(x2, w_u2, g_c, b_c, st, out, M);
    k8_elem<<<2048, 256, 0, stream>>>(s_feats, g_u2, b_u2, st, out, M);
}